// Round 10
// baseline (11579.676 us; speedup 1.0000x reference)
//
#include <hip/hip_runtime.h>
#include <math.h>

#define NBLK 256
#define NTHR 512
#define Bz 128
#define Mz 64
#define Sz 1024
#define Hz 512
#define HB (Hz*Bz)

typedef float        f32x4 __attribute__((ext_vector_type(4)));
typedef short        s16x8 __attribute__((ext_vector_type(8)));
typedef unsigned int u32x4 __attribute__((ext_vector_type(4)));

__device__ __forceinline__ float sigm_(float x){ return 1.0f/(1.0f + __expf(-x)); }
__device__ __forceinline__ float tanh_(float x){
  float e = __expf(-2.0f*fabsf(x));
  float t2 = (1.0f - e)/(1.0f + e);
  return copysignf(t2, x);
}
__device__ __forceinline__ unsigned f2bf(float x){           // RNE f32->bf16 bits
  unsigned u = __float_as_uint(x);
  return (u + 0x7fffu + ((u>>16)&1u)) >> 16;
}
__device__ __forceinline__ float bf2f(unsigned h){ return __uint_as_float(h<<16); }
__device__ __forceinline__ unsigned packh(float x){          // hi | lo<<16
  unsigned hi = f2bf(x);
  unsigned lo = f2bf(x - bf2f(hi));
  return hi | (lo<<16);
}

// ---- coherence primitives (R0/R3/R7-proven MALL path) ----
__device__ __forceinline__ void st_flag(int* p, int v){
  asm volatile("global_store_dword %0, %1, off sc0 sc1\n\ts_waitcnt vmcnt(0)"
               :: "v"(p), "v"(v) : "memory");
}
__device__ __forceinline__ int ld_flag(const int* p){
  int v;
  asm volatile("global_load_dword %0, %1, off sc0 sc1\n\ts_waitcnt vmcnt(0)"
               : "=v"(v) : "v"(p) : "memory");
  return v;
}
__device__ __forceinline__ void sth_u(unsigned* p, unsigned v){
  __hip_atomic_store(p, v, __ATOMIC_RELAXED, __HIP_MEMORY_SCOPE_AGENT);
}
__device__ __forceinline__ unsigned ldh_u(const unsigned* p){
  return __hip_atomic_load(p, __ATOMIC_RELAXED, __HIP_MEMORY_SCOPE_AGENT);
}

// counted async loads: NO self-wait; paired with manual s_waitcnt vmcnt(N).
// HARD RULE (R8/R9 post-mortems): destinations of these loads must live in
// NAMED register sets, never runtime-indexed arrays — a scratch spill reads
// the dest before the load lands. va..vd below are load-bearing structure.
__device__ __forceinline__ unsigned ld_h1(const unsigned* p){   // L3-coherent h read
  unsigned r;
  asm volatile("global_load_dword %0, %1, off sc0 sc1" : "=v"(r) : "v"(p) : "memory");
  return r;
}
__device__ __forceinline__ void ld_e4(u32x4& d, const float* p){ // cached emb read (counted)
  asm volatile("global_load_dwordx4 %0, %1, off" : "=v"(d) : "v"(p) : "memory");
}
__device__ __forceinline__ void wait_vm(int n){   // n is block-uniform; exact cases only
  switch(n){
    case 0:  asm volatile("s_waitcnt vmcnt(0)"  ::: "memory"); break;
    case 6:  asm volatile("s_waitcnt vmcnt(6)"  ::: "memory"); break;
    case 8:  asm volatile("s_waitcnt vmcnt(8)"  ::: "memory"); break;
    case 12: asm volatile("s_waitcnt vmcnt(12)" ::: "memory"); break;
    case 16: asm volatile("s_waitcnt vmcnt(16)" ::: "memory"); break;
    case 18: asm volatile("s_waitcnt vmcnt(18)" ::: "memory"); break;
    default: asm volatile("s_waitcnt vmcnt(0)"  ::: "memory"); break;  // conservative
  }
}
// block barrier WITHOUT vmcnt drain (keeps prefetch loads in flight)
__device__ __forceinline__ void barrier_fast(){
  asm volatile("s_waitcnt lgkmcnt(0)\n\ts_barrier" ::: "memory");
}

// LDS map (bytes) — identical to R7:
//   [0,32768)        A double-buffer: buf*16384 + plane(hi/lo)*8192 ; 64k x 64b x bf16
//   [32768,98304)    W_hi frags: (ksG*2+tile)*1024 + lane*16
//   [98304,163840)   W_lo frags
//   zbuf (8KB) aliases [0,8192) after the K-loop (last chunk odd -> reads buf1).
#define A_OFF   0
#define WHI_OFF 32768
#define WLO_OFF 98304
#define SHMEM   163840

extern "C" __global__ void __launch_bounds__(NTHR, 1)
qlstm_kern(const int* __restrict__ x, const float* __restrict__ emb,
           const float* __restrict__ W0, const float* __restrict__ b0v, const float* __restrict__ bb0v,
           const float* __restrict__ W1, const float* __restrict__ b1v, const float* __restrict__ bb1v,
           const float* __restrict__ fcw, const float* __restrict__ fcb,
           float* __restrict__ out, float* __restrict__ ws)
{
  extern __shared__ char sm[];
  const int t   = threadIdx.x;
  const int bid = blockIdx.x;
  const bool isL0 = (bid < 128);
  const int lb    = isL0 ? bid : bid - 128;
  const int gbase = (lb >> 1) * 8;          // 8 hidden cols per block
  const int mb    = (lb & 1) * Mz;          // batch half (64 rows)
  const int K  = isL0 ? 768 : 1024;
  const int KS = K >> 5;                    // 32-k steps (W frag granularity)
  const int NCh = K >> 6;                   // 64-k chunks: L0 12, L1 16 (both %4==0)

  const int lane = t & 63;
  const int w    = t >> 6;                  // wave id 0..7
  const int mt   = w & 3;                   // M-tile (16 rows of 64)
  const int nt   = w >> 2;                  // N-tile (16 of 32 cols)
  const int m16  = lane & 15;
  const int q4   = lane >> 4;
  const int aoff = (q4*64 + mt*16 + m16) * 16;  // A-frag byte offset within (buf,plane,ks)
  const int boff = lane * 16;                   // B-frag byte offset within (ksG,tile)

  const int b_s = t & 63;            // stager: batch column (within block's 64)
  const int g0  = t >> 6;            // stager: 8-k group within 64-k chunk

  const int b_c = t >> 3;            // cell thread: batch (0..63)
  const int hl  = t & 7;             // cell thread: local hidden col (0..7)

  unsigned* h0s = (unsigned*)ws;           // 2 bufs of [Hz][Bz] packed bf16-pairs
  unsigned* h1s = h0s + 2*HB;
  int* flags = (int*)(h0s + 4*HB);

  // zero h state through the coherent path
  for (int i = bid*NTHR + t; i < 4*HB; i += NBLK*NTHR) sth_u(&h0s[i], 0u);

  // x-row prefetch register (L0 only): holds x[mb+b_s, p] for the upcoming step
  int xrow_nx = 0;
  if (isL0) xrow_nx = x[(mb + b_s)*Sz];

  // ---- one-time W -> LDS B-fragment layout (hi/lo bf16 planes, 2 N-tiles) ----
  {
    const float* Wsrc = isL0 ? W0 : W1;
    const int gtot = KS * 128;               // g = kc*128 + tile*64 + q*16 + n
    for (int g = t; g < gtot; g += NTHR){
      const int kc = g >> 7, rem = g & 127;
      const int tile = rem >> 6, q = (rem >> 4) & 3, n = rem & 15;
      const int zrow = (n & 3)*Hz + gbase + tile*4 + (n >> 2);  // gate = n&3, hid = tile*4 + n>>2
      const float* src = Wsrc + (size_t)zrow*K + kc*32 + q*8;
      const float4 e0 = *(const float4*)(src);
      const float4 e1 = *(const float4*)(src + 4);
      float ev[8] = {e0.x,e0.y,e0.z,e0.w,e1.x,e1.y,e1.z,e1.w};
      unsigned hiw[4], low[4];
      #pragma unroll
      for (int k2 = 0; k2 < 4; ++k2){
        unsigned ha = f2bf(ev[2*k2]),   hb = f2bf(ev[2*k2+1]);
        unsigned la = f2bf(ev[2*k2]   - bf2f(ha));
        unsigned lb = f2bf(ev[2*k2+1] - bf2f(hb));
        hiw[k2] = ha | (hb << 16);
        low[k2] = la | (lb << 16);
      }
      *(u32x4*)(sm + WHI_OFF + g*16) = (u32x4){hiw[0],hiw[1],hiw[2],hiw[3]};
      *(u32x4*)(sm + WLO_OFF + g*16) = (u32x4){low[0],low[1],low[2],low[3]};
    }
  }

  // bias per cell thread: 4 gates of hidden col gbase+hl
  const float* bsrc  = isL0 ? b0v  : b1v;
  const float* bbsrc = isL0 ? bb0v : bb1v;
  float bias[4];
  #pragma unroll
  for (int g = 0; g < 4; ++g)
    bias[g] = bsrc[g*Hz + gbase + hl] + bbsrc[g*Hz + gbase + hl];

  float creg = 0.0f;
  __syncthreads();

  auto gridbar = [&](int epoch){
    __syncthreads();                       // full drain incl. vmcnt (h stores reach MALL)
    if (t == 0){
      __builtin_amdgcn_s_waitcnt(0x0F70);  // vmcnt(0) belt-and-braces
      st_flag(&flags[bid], epoch);
    }
    if (t < NBLK){
      while (ld_flag(&flags[t]) < epoch) __builtin_amdgcn_s_sleep(4);
    }
    __syncthreads();
  };

  gridbar(1);

  for (int p = 0; p <= Sz; ++p){
    const int rb = (p + 1) & 1;
    const int wb = p & 1;
    const bool active = isL0 ? (p < Sz) : (p >= 1);
    if (active){
      const unsigned* h0r = h0s + rb*HB;
      const unsigned* h1r = h1s + rb*HB;
      const float* embrow = emb;
      if (isL0){
        embrow = emb + (size_t)xrow_nx * 256;   // row prefetched last step (drained by gridbar)
      }
      asm volatile("s_waitcnt vmcnt(0)" ::: "memory");   // clean counter baseline

      u32x4 va[2], vb[2], vc[2], vd[2];     // NAMED 4-deep pipeline (R7-proven)
      f32x4 accP = {0.f, 0.f, 0.f, 0.f};    // tri accumulators: dep chain 2 MFMAs each
      f32x4 accQ = {0.f, 0.f, 0.f, 0.f};
      f32x4 accR = {0.f, 0.f, 0.f, 0.f};

      // per-thread chunk load: 8 k for batch mb+b_s (emb: 2x dwordx4; h: 8x dword)
      auto LD = [&](int c, u32x4 (&v)[2]){
        const int kg = c*64 + g0*8;
        if (isL0 && c < 4){
          ld_e4(v[0], embrow + kg);
          ld_e4(v[1], embrow + kg + 4);
        } else {
          const unsigned* src;
          if (isL0)          src = h0r + (kg - 256)*Bz + mb + b_s;
          else if (kg < Hz)  src = h0r + kg*Bz + mb + b_s;
          else               src = h1r + (kg - Hz)*Bz + mb + b_s;
          #pragma unroll
          for (int j = 0; j < 8; ++j){
            unsigned r = ld_h1(src + j*Bz);
            v[j>>2][j & 3] = r;
          }
        }
      };

      auto WR = [&](int c, u32x4 (&v)[2]){
        char* Ah = sm + A_OFF + (c & 1)*16384;
        char* Al = Ah + 8192;
        unsigned s[8];
        #pragma unroll
        for (int j = 0; j < 8; ++j) s[j] = v[j>>2][j & 3];
        unsigned hiw[4], low[4];
        if (isL0 && c < 4){
          #pragma unroll
          for (int k2 = 0; k2 < 4; ++k2){
            float ea = __uint_as_float(s[2*k2]), eb = __uint_as_float(s[2*k2+1]);
            unsigned ha = f2bf(ea), hb = f2bf(eb);
            unsigned la = f2bf(ea - bf2f(ha)), lb = f2bf(eb - bf2f(hb));
            hiw[k2] = ha | (hb << 16);
            low[k2] = la | (lb << 16);
          }
        } else {
          #pragma unroll
          for (int k2 = 0; k2 < 4; ++k2){
            hiw[k2] = (s[2*k2] & 0xffffu) | (s[2*k2+1] << 16);
            low[k2] = (s[2*k2] >> 16)     | (s[2*k2+1] & 0xffff0000u);
          }
        }
        const int off = (g0*64 + b_s) * 16;
        *(u32x4*)(Ah + off) = (u32x4){hiw[0],hiw[1],hiw[2],hiw[3]};
        *(u32x4*)(Al + off) = (u32x4){low[0],low[1],low[2],low[3]};
      };

      // tri-accumulator CMP: same 6 products; chains P:2, Q:2, R:2; z = P+Q+R.
      auto CMP = [&](int c){
        const char* Ab = sm + A_OFF + (c & 1)*16384 + aoff;
        #pragma unroll
        for (int ks = 0; ks < 2; ++ks){
          u32x4 ah = *(const u32x4*)(Ab + ks*4096);
          u32x4 al = *(const u32x4*)(Ab + 8192 + ks*4096);
          u32x4 bh = *(const u32x4*)(sm + WHI_OFF + ((c*2 + ks)*2 + nt)*1024 + boff);
          u32x4 bl = *(const u32x4*)(sm + WLO_OFF + ((c*2 + ks)*2 + nt)*1024 + boff);
          s16x8 fah = __builtin_bit_cast(s16x8, ah);
          s16x8 fal = __builtin_bit_cast(s16x8, al);
          s16x8 fbh = __builtin_bit_cast(s16x8, bh);
          s16x8 fbl = __builtin_bit_cast(s16x8, bl);
          accP = __builtin_amdgcn_mfma_f32_16x16x32_bf16(fah, fbh, accP, 0, 0, 0);
          accQ = __builtin_amdgcn_mfma_f32_16x16x32_bf16(fah, fbl, accQ, 0, 0, 0);
          accR = __builtin_amdgcn_mfma_f32_16x16x32_bf16(fal, fbh, accR, 0, 0, 0);
        }
      };

      auto CNT = [&](int c)->int{
        if (c >= NCh) return 0;
        return (isL0 && c < 4) ? 2 : 8;
      };
      auto W3 = [&](int c)->int{ return CNT(c+1) + CNT(c+2) + CNT(c+3); };

      // 4-deep register pipeline; one barrier per chunk (barrier before CMP(c+1)
      // orders all waves' CMP(c) lds-reads before WR(c+2) rewrites that buffer).
      LD(0, va); LD(1, vb); LD(2, vc); LD(3, vd);
      for (int c = 0; c < NCh; c += 4){
        wait_vm(W3(c));   WR(c,   va); if (c+4 < NCh) LD(c+4, va);
        barrier_fast(); CMP(c);
        wait_vm(W3(c+1)); WR(c+1, vb); if (c+5 < NCh) LD(c+5, vb);
        barrier_fast(); CMP(c+1);
        wait_vm(W3(c+2)); WR(c+2, vc); if (c+6 < NCh) LD(c+6, vc);
        barrier_fast(); CMP(c+2);
        wait_vm(W3(c+3)); WR(c+3, vd); if (c+7 < NCh) LD(c+7, vd);
        barrier_fast(); CMP(c+3);
      }

      // ---- epilogue: z -> LDS (aliases A buf0; last CMP reads buf1), cell, h store ----
      {
        const f32x4 acc = (accP + accQ) + accR;
        float* zb = (float*)sm;
        #pragma unroll
        for (int r = 0; r < 4; ++r){
          const int b_z = mt*16 + q4*4 + r;
          zb[b_z*32 + nt*16 + m16] = acc[r];
        }
      }
      __syncthreads();
      {
        const float* zrow = (const float*)sm + b_c*32 + hl*4;
        const f32x4 z = *(const f32x4*)(zrow);   // gates f,i,c,o of (b_c, hl)
        const float fg = sigm_(z[0] + bias[0]);
        const float ig = sigm_(z[1] + bias[1]);
        const float cg = tanh_(z[2] + bias[2]);
        const float og = sigm_(z[3] + bias[3]);
        creg = fg*creg + ig*cg;
        const float hval = og * tanh_(creg);
        unsigned* hdst = (isL0 ? h0s : h1s) + wb*HB;
        sth_u(&hdst[(gbase + hl)*Bz + mb + b_c], packh(hval));
        // prefetch next step's x row; completes under the grid barrier drain
        if (isL0 && (p + 1) < Sz){
          asm volatile("global_load_dword %0, %1, off"
                       : "=v"(xrow_nx) : "v"(x + (mb + b_s)*Sz + p + 1) : "memory");
        }
      }
    }
    gridbar(p + 2);
  }

  // final FC: out[b][o] = h1 . fc_w[o] + fc_b[o]; final h1 in buf 0 (Sz even)
  if (bid == 0 && t < 2*Bz){
    const int ob = t >> 1, oo = t & 1;
    const unsigned* hf = h1s;
    float a = fcb[oo];
    #pragma unroll 8
    for (int h = 0; h < Hz; ++h){
      const unsigned pv = ldh_u(&hf[h*Bz + ob]);
      a += (bf2f(pv & 0xffffu) + bf2f(pv >> 16)) * fcw[oo*Hz + h];
    }
    out[ob*2 + oo] = a;
  }
}

extern "C" void kernel_launch(void* const* d_in, const int* in_sizes, int n_in,
                              void* d_out, int out_size, void* d_ws, size_t ws_size,
                              hipStream_t stream) {
  (void)in_sizes; (void)n_in; (void)out_size; (void)ws_size;
  const int*   x   = (const int*)d_in[0];
  const float* emb = (const float*)d_in[1];
  const float* W0  = (const float*)d_in[2];
  const float* b0  = (const float*)d_in[3];
  const float* bb0 = (const float*)d_in[4];
  const float* W1  = (const float*)d_in[5];
  const float* b1  = (const float*)d_in[6];
  const float* bb1 = (const float*)d_in[7];
  const float* fcw = (const float*)d_in[8];
  const float* fcb = (const float*)d_in[9];
  float* out = (float*)d_out;
  float* ws  = (float*)d_ws;

  const size_t shmem = SHMEM;   // 32KB A dbuf + 64KB W_hi + 64KB W_lo = 160KiB
  hipFuncSetAttribute((const void*)qlstm_kern,
                      hipFuncAttributeMaxDynamicSharedMemorySize, (int)shmem);

  void* args[] = { (void*)&x, (void*)&emb, (void*)&W0, (void*)&b0, (void*)&bb0,
                   (void*)&W1, (void*)&b1, (void*)&bb1, (void*)&fcw, (void*)&fcb,
                   (void*)&out, (void*)&ws };
  hipLaunchCooperativeKernel((const void*)qlstm_kern, dim3(NBLK), dim3(NTHR),
                             args, (unsigned)shmem, stream);
}

// Round 11
// 10932.648 us; speedup vs baseline: 1.0592x; 1.0592x over previous
//
#include <hip/hip_runtime.h>
#include <math.h>

#define NBLK 256
#define NTHR 512
#define Bz 128
#define Mz 64
#define Sz 1024
#define Hz 512
#define HB (Hz*Bz)

typedef float        f32x4 __attribute__((ext_vector_type(4)));
typedef short        s16x8 __attribute__((ext_vector_type(8)));
typedef unsigned int u32x4 __attribute__((ext_vector_type(4)));

__device__ __forceinline__ float sigm_(float x){ return 1.0f/(1.0f + __expf(-x)); }
__device__ __forceinline__ float tanh_(float x){
  float e = __expf(-2.0f*fabsf(x));
  float t2 = (1.0f - e)/(1.0f + e);
  return copysignf(t2, x);
}
__device__ __forceinline__ unsigned f2bf(float x){           // RNE f32->bf16 bits
  unsigned u = __float_as_uint(x);
  return (u + 0x7fffu + ((u>>16)&1u)) >> 16;
}
__device__ __forceinline__ float bf2f(unsigned h){ return __uint_as_float(h<<16); }
__device__ __forceinline__ unsigned packh(float x){          // hi | lo<<16
  unsigned hi = f2bf(x);
  unsigned lo = f2bf(x - bf2f(hi));
  return hi | (lo<<16);
}

// ---- coherence primitives (R0/R3/R7-proven MALL path) ----
__device__ __forceinline__ void st_flag(int* p, int v){
  asm volatile("global_store_dword %0, %1, off sc0 sc1\n\ts_waitcnt vmcnt(0)"
               :: "v"(p), "v"(v) : "memory");
}
__device__ __forceinline__ int ld_flag(const int* p){
  int v;
  asm volatile("global_load_dword %0, %1, off sc0 sc1\n\ts_waitcnt vmcnt(0)"
               : "=v"(v) : "v"(p) : "memory");
  return v;
}
__device__ __forceinline__ void sth_u(unsigned* p, unsigned v){
  __hip_atomic_store(p, v, __ATOMIC_RELAXED, __HIP_MEMORY_SCOPE_AGENT);
}
__device__ __forceinline__ unsigned ldh_u(const unsigned* p){
  return __hip_atomic_load(p, __ATOMIC_RELAXED, __HIP_MEMORY_SCOPE_AGENT);
}

// counted async loads: NO self-wait; paired with manual s_waitcnt vmcnt(N).
// HARD RULE (R8/R9 post-mortems): destinations of these loads must live in
// NAMED register sets, never runtime-indexed arrays — a scratch spill reads
// the dest before the load lands. va..vd below are load-bearing structure.
__device__ __forceinline__ unsigned ld_h1(const unsigned* p){   // L3-coherent h read
  unsigned r;
  asm volatile("global_load_dword %0, %1, off sc0 sc1" : "=v"(r) : "v"(p) : "memory");
  return r;
}
__device__ __forceinline__ void ld_e4(u32x4& d, const float* p){ // cached emb read (counted)
  asm volatile("global_load_dwordx4 %0, %1, off" : "=v"(d) : "v"(p) : "memory");
}
__device__ __forceinline__ void wait_vm(int n){   // n is block-uniform; exact cases only
  switch(n){
    case 0:  asm volatile("s_waitcnt vmcnt(0)"  ::: "memory"); break;
    case 6:  asm volatile("s_waitcnt vmcnt(6)"  ::: "memory"); break;
    case 8:  asm volatile("s_waitcnt vmcnt(8)"  ::: "memory"); break;
    case 12: asm volatile("s_waitcnt vmcnt(12)" ::: "memory"); break;
    case 16: asm volatile("s_waitcnt vmcnt(16)" ::: "memory"); break;
    case 18: asm volatile("s_waitcnt vmcnt(18)" ::: "memory"); break;
    default: asm volatile("s_waitcnt vmcnt(24)" ::: "memory"); break;
  }
}
// block barrier WITHOUT vmcnt drain (keeps prefetch loads in flight)
__device__ __forceinline__ void barrier_fast(){
  asm volatile("s_waitcnt lgkmcnt(0)\n\ts_barrier" ::: "memory");
}

// LDS map (bytes):
//   [0,32768)        A double-buffer: buf*16384 + plane(hi/lo)*8192 ; 64k x 64b x bf16
//   [32768,98304)    W_hi frags: (ksG*2+tile)*1024 + lane*16
//   [98304,163840)   W_lo frags
//   zbuf (8KB) aliases [0,8192) after the K-loop (last chunk odd -> reads buf1).
#define A_OFF   0
#define WHI_OFF 32768
#define WLO_OFF 98304
#define SHMEM   163840

extern "C" __global__ void __launch_bounds__(NTHR, 1)
qlstm_kern(const int* __restrict__ x, const float* __restrict__ emb,
           const float* __restrict__ W0, const float* __restrict__ b0v, const float* __restrict__ bb0v,
           const float* __restrict__ W1, const float* __restrict__ b1v, const float* __restrict__ bb1v,
           const float* __restrict__ fcw, const float* __restrict__ fcb,
           float* __restrict__ out, float* __restrict__ ws)
{
  extern __shared__ char sm[];
  const int t   = threadIdx.x;
  const int bid = blockIdx.x;
  const bool isL0 = (bid < 128);
  const int lb    = isL0 ? bid : bid - 128;
  const int gbase = (lb >> 1) * 8;          // 8 hidden cols per block
  const int mb    = (lb & 1) * Mz;          // batch half (64 rows)
  const int K  = isL0 ? 768 : 1024;
  const int KS = K >> 5;                    // 32-k steps (W frag granularity)
  const int NCh = K >> 6;                   // 64-k chunks: L0 12, L1 16 (both %4==0)

  const int lane = t & 63;
  const int w    = t >> 6;                  // wave id 0..7
  const int mt   = w & 3;                   // M-tile (16 rows of 64)
  const int nt   = w >> 2;                  // N-tile (16 of 32 cols)
  const int m16  = lane & 15;
  const int q4   = lane >> 4;
  const int aoff = (q4*64 + mt*16 + m16) * 16;  // A-frag byte offset within (buf,plane,ks)
  const int boff = lane * 16;                   // B-frag byte offset within (ksG,tile)

  const int b_s = t & 63;            // stager: batch column (within block's 64)
  const int g0  = t >> 6;            // stager: 8-k group within 64-k chunk

  const int b_c = t >> 3;            // cell thread: batch (0..63)
  const int hl  = t & 7;             // cell thread: local hidden col (0..7)

  unsigned* h0s = (unsigned*)ws;           // 2 bufs of [Hz][Bz] packed bf16-pairs
  unsigned* h1s = h0s + 2*HB;
  int* flags = (int*)(h0s + 4*HB);

  // zero h state through the coherent path
  for (int i = bid*NTHR + t; i < 4*HB; i += NBLK*NTHR) sth_u(&h0s[i], 0u);

  // x-row prefetch register (L0 only): holds x[mb+b_s, p] for the upcoming step
  int xrow_nx = 0;
  if (isL0) xrow_nx = x[(mb + b_s)*Sz];

  // ---- one-time W -> LDS B-fragment layout (hi/lo bf16 planes, 2 N-tiles) ----
  {
    const float* Wsrc = isL0 ? W0 : W1;
    const int gtot = KS * 128;               // g = kc*128 + tile*64 + q*16 + n
    for (int g = t; g < gtot; g += NTHR){
      const int kc = g >> 7, rem = g & 127;
      const int tile = rem >> 6, q = (rem >> 4) & 3, n = rem & 15;
      const int zrow = (n & 3)*Hz + gbase + tile*4 + (n >> 2);  // gate = n&3, hid = tile*4 + n>>2
      const float* src = Wsrc + (size_t)zrow*K + kc*32 + q*8;
      const float4 e0 = *(const float4*)(src);
      const float4 e1 = *(const float4*)(src + 4);
      float ev[8] = {e0.x,e0.y,e0.z,e0.w,e1.x,e1.y,e1.z,e1.w};
      unsigned hiw[4], low[4];
      #pragma unroll
      for (int k2 = 0; k2 < 4; ++k2){
        unsigned ha = f2bf(ev[2*k2]),   hb = f2bf(ev[2*k2+1]);
        unsigned la = f2bf(ev[2*k2]   - bf2f(ha));
        unsigned lb = f2bf(ev[2*k2+1] - bf2f(hb));
        hiw[k2] = ha | (hb << 16);
        low[k2] = la | (lb << 16);
      }
      *(u32x4*)(sm + WHI_OFF + g*16) = (u32x4){hiw[0],hiw[1],hiw[2],hiw[3]};
      *(u32x4*)(sm + WLO_OFF + g*16) = (u32x4){low[0],low[1],low[2],low[3]};
    }
  }

  // bias per cell thread: 4 gates of hidden col gbase+hl
  const float* bsrc  = isL0 ? b0v  : b1v;
  const float* bbsrc = isL0 ? bb0v : bb1v;
  float bias[4];
  #pragma unroll
  for (int g = 0; g < 4; ++g)
    bias[g] = bsrc[g*Hz + gbase + hl] + bbsrc[g*Hz + gbase + hl];

  float creg = 0.0f;
  __syncthreads();

  auto gridbar = [&](int epoch){
    __syncthreads();                       // full drain incl. vmcnt (h stores reach MALL)
    if (t == 0){
      __builtin_amdgcn_s_waitcnt(0x0F70);  // vmcnt(0) belt-and-braces
      st_flag(&flags[bid], epoch);
    }
    if (t < NBLK){
      while (ld_flag(&flags[t]) < epoch) __builtin_amdgcn_s_sleep(4);
    }
    __syncthreads();
  };

  gridbar(1);

  for (int p = 0; p <= Sz; ++p){
    const int rb = (p + 1) & 1;
    const int wb = p & 1;
    const bool active = isL0 ? (p < Sz) : (p >= 1);
    if (active){
      const unsigned* h0r = h0s + rb*HB;
      const unsigned* h1r = h1s + rb*HB;
      const float* embrow = emb;
      if (isL0){
        embrow = emb + (size_t)xrow_nx * 256;   // row prefetched last step (drained by gridbar)
      }
      asm volatile("s_waitcnt vmcnt(0)" ::: "memory");   // clean counter baseline

      u32x4 va[2], vb[2], vc[2], vd[2];
      f32x4 accP = {0.f, 0.f, 0.f, 0.f};   // dual accumulators: halve the exposed
      f32x4 accQ = {0.f, 0.f, 0.f, 0.f};   // dependent-MFMA chain per chunk

      // per-thread chunk load: 8 k for batch mb+b_s (emb: 2x dwordx4; h: 8x dword)
      auto LD = [&](int c, u32x4 (&v)[2]){
        const int kg = c*64 + g0*8;
        if (isL0 && c < 4){
          ld_e4(v[0], embrow + kg);
          ld_e4(v[1], embrow + kg + 4);
        } else {
          const unsigned* src;
          if (isL0)          src = h0r + (kg - 256)*Bz + mb + b_s;
          else if (kg < Hz)  src = h0r + kg*Bz + mb + b_s;
          else               src = h1r + (kg - Hz)*Bz + mb + b_s;
          #pragma unroll
          for (int j = 0; j < 8; ++j){
            unsigned r = ld_h1(src + j*Bz);
            v[j>>2][j & 3] = r;
          }
        }
      };

      auto WR = [&](int c, u32x4 (&v)[2]){
        char* Ah = sm + A_OFF + (c & 1)*16384;
        char* Al = Ah + 8192;
        unsigned s[8];
        #pragma unroll
        for (int j = 0; j < 8; ++j) s[j] = v[j>>2][j & 3];
        unsigned hiw[4], low[4];
        if (isL0 && c < 4){
          #pragma unroll
          for (int k2 = 0; k2 < 4; ++k2){
            float ea = __uint_as_float(s[2*k2]), eb = __uint_as_float(s[2*k2+1]);
            unsigned ha = f2bf(ea), hb = f2bf(eb);
            unsigned la = f2bf(ea - bf2f(ha)), lb = f2bf(eb - bf2f(hb));
            hiw[k2] = ha | (hb << 16);
            low[k2] = la | (lb << 16);
          }
        } else {
          #pragma unroll
          for (int k2 = 0; k2 < 4; ++k2){
            hiw[k2] = (s[2*k2] & 0xffffu) | (s[2*k2+1] << 16);
            low[k2] = (s[2*k2] >> 16)     | (s[2*k2+1] & 0xffff0000u);
          }
        }
        const int off = (g0*64 + b_s) * 16;
        *(u32x4*)(Ah + off) = (u32x4){hiw[0],hiw[1],hiw[2],hiw[3]};
        *(u32x4*)(Al + off) = (u32x4){low[0],low[1],low[2],low[3]};
      };

      // dual-accumulator CMP: same 6 products, alternated P/Q (3+3); z = P+Q.
      auto CMP = [&](int c){
        const char* Ab = sm + A_OFF + (c & 1)*16384 + aoff;
        #pragma unroll
        for (int ks = 0; ks < 2; ++ks){
          u32x4 ah = *(const u32x4*)(Ab + ks*4096);
          u32x4 al = *(const u32x4*)(Ab + 8192 + ks*4096);
          u32x4 bh = *(const u32x4*)(sm + WHI_OFF + ((c*2 + ks)*2 + nt)*1024 + boff);
          u32x4 bl = *(const u32x4*)(sm + WLO_OFF + ((c*2 + ks)*2 + nt)*1024 + boff);
          s16x8 fah = __builtin_bit_cast(s16x8, ah);
          s16x8 fal = __builtin_bit_cast(s16x8, al);
          s16x8 fbh = __builtin_bit_cast(s16x8, bh);
          s16x8 fbl = __builtin_bit_cast(s16x8, bl);
          if (ks == 0){
            accP = __builtin_amdgcn_mfma_f32_16x16x32_bf16(fah, fbh, accP, 0, 0, 0);
            accQ = __builtin_amdgcn_mfma_f32_16x16x32_bf16(fah, fbl, accQ, 0, 0, 0);
            accP = __builtin_amdgcn_mfma_f32_16x16x32_bf16(fal, fbh, accP, 0, 0, 0);
          } else {
            accQ = __builtin_amdgcn_mfma_f32_16x16x32_bf16(fah, fbh, accQ, 0, 0, 0);
            accP = __builtin_amdgcn_mfma_f32_16x16x32_bf16(fah, fbl, accP, 0, 0, 0);
            accQ = __builtin_amdgcn_mfma_f32_16x16x32_bf16(fal, fbh, accQ, 0, 0, 0);
          }
        }
      };

      auto CNT = [&](int c)->int{
        if (c >= NCh) return 0;
        return (isL0 && c < 4) ? 2 : 8;
      };
      auto W3 = [&](int c)->int{ return CNT(c+1) + CNT(c+2) + CNT(c+3); };

      // 4-deep register pipeline; one barrier per chunk (barrier before CMP(c+1)
      // orders all waves' CMP(c) lds-reads before WR(c+2) rewrites that buffer).
      LD(0, va); LD(1, vb); LD(2, vc); LD(3, vd);
      for (int c = 0; c < NCh; c += 4){
        wait_vm(W3(c));   WR(c,   va); if (c+4 < NCh) LD(c+4, va);
        barrier_fast(); CMP(c);
        wait_vm(W3(c+1)); WR(c+1, vb); if (c+5 < NCh) LD(c+5, vb);
        barrier_fast(); CMP(c+1);
        wait_vm(W3(c+2)); WR(c+2, vc); if (c+6 < NCh) LD(c+6, vc);
        barrier_fast(); CMP(c+2);
        wait_vm(W3(c+3)); WR(c+3, vd); if (c+7 < NCh) LD(c+7, vd);
        barrier_fast(); CMP(c+3);
      }

      // ---- epilogue: z -> LDS (aliases A buf0; last CMP reads buf1), cell, h store ----
      {
        const f32x4 acc = accP + accQ;
        float* zb = (float*)sm;
        #pragma unroll
        for (int r = 0; r < 4; ++r){
          const int b_z = mt*16 + q4*4 + r;
          zb[b_z*32 + nt*16 + m16] = acc[r];
        }
      }
      __syncthreads();
      {
        const float* zrow = (const float*)sm + b_c*32 + hl*4;
        const f32x4 z = *(const f32x4*)(zrow);   // gates f,i,c,o of (b_c, hl)
        const float fg = sigm_(z[0] + bias[0]);
        const float ig = sigm_(z[1] + bias[1]);
        const float cg = tanh_(z[2] + bias[2]);
        const float og = sigm_(z[3] + bias[3]);
        creg = fg*creg + ig*cg;
        const float hval = og * tanh_(creg);
        unsigned* hdst = (isL0 ? h0s : h1s) + wb*HB;
        sth_u(&hdst[(gbase + hl)*Bz + mb + b_c], packh(hval));
        // prefetch next step's x row; completes under the grid barrier drain
        if (isL0 && (p + 1) < Sz){
          asm volatile("global_load_dword %0, %1, off"
                       : "=v"(xrow_nx) : "v"(x + (mb + b_s)*Sz + p + 1) : "memory");
        }
      }
    }
    gridbar(p + 2);
  }

  // final FC: out[b][o] = h1 . fc_w[o] + fc_b[o]; final h1 in buf 0 (Sz even)
  if (bid == 0 && t < 2*Bz){
    const int ob = t >> 1, oo = t & 1;
    const unsigned* hf = h1s;
    float a = fcb[oo];
    #pragma unroll 8
    for (int h = 0; h < Hz; ++h){
      const unsigned pv = ldh_u(&hf[h*Bz + ob]);
      a += (bf2f(pv & 0xffffu) + bf2f(pv >> 16)) * fcw[oo*Hz + h];
    }
    out[ob*2 + oo] = a;
  }
}

extern "C" void kernel_launch(void* const* d_in, const int* in_sizes, int n_in,
                              void* d_out, int out_size, void* d_ws, size_t ws_size,
                              hipStream_t stream) {
  (void)in_sizes; (void)n_in; (void)out_size; (void)ws_size;
  const int*   x   = (const int*)d_in[0];
  const float* emb = (const float*)d_in[1];
  const float* W0  = (const float*)d_in[2];
  const float* b0  = (const float*)d_in[3];
  const float* bb0 = (const float*)d_in[4];
  const float* W1  = (const float*)d_in[5];
  const float* b1  = (const float*)d_in[6];
  const float* bb1 = (const float*)d_in[7];
  const float* fcw = (const float*)d_in[8];
  const float* fcb = (const float*)d_in[9];
  float* out = (float*)d_out;
  float* ws  = (float*)d_ws;

  const size_t shmem = SHMEM;   // 32KB A dbuf + 64KB W_hi + 64KB W_lo = 160KiB
  hipFuncSetAttribute((const void*)qlstm_kern,
                      hipFuncAttributeMaxDynamicSharedMemorySize, (int)shmem);

  void* args[] = { (void*)&x, (void*)&emb, (void*)&W0, (void*)&b0, (void*)&bb0,
                   (void*)&W1, (void*)&b1, (void*)&bb1, (void*)&fcw, (void*)&fcb,
                   (void*)&out, (void*)&ws };
  hipLaunchCooperativeKernel((const void*)qlstm_kern, dim3(NBLK), dim3(NTHR),
                             args, (unsigned)shmem, stream);
}